// Round 1
// baseline (1744.845 us; speedup 1.0000x reference)
//
#include <hip/hip_runtime.h>
#include <hip/hip_bf16.h>
#include <math.h>

#define HID 256
#define NTHREADS 256

// ---------------------------------------------------------------- edge prep

__global__ void hist_kernel(const int* __restrict__ dst, int* __restrict__ deg, int E) {
    int e = blockIdx.x * blockDim.x + threadIdx.x;
    if (e < E) atomicAdd(&deg[dst[e]], 1);
}

__global__ __launch_bounds__(1024) void scan_kernel(const int* __restrict__ deg,
        int* __restrict__ rowptr, int* __restrict__ cursor,
        float* __restrict__ dinv, int N) {
    __shared__ int ssum[1024];
    int tid = threadIdx.x;
    int chunk = (N + 1023) / 1024;
    int lo = tid * chunk, hi = min(lo + chunk, N);
    int local = 0;
    for (int i = lo; i < hi; i++) local += deg[i];
    ssum[tid] = local;
    __syncthreads();
    for (int off = 1; off < 1024; off <<= 1) {
        int v = (tid >= off) ? ssum[tid - off] : 0;
        __syncthreads();
        ssum[tid] += v;
        __syncthreads();
    }
    int run = ssum[tid] - local;  // exclusive prefix
    for (int i = lo; i < hi; i++) {
        int d = deg[i];
        rowptr[i] = run;
        cursor[i] = run;
        dinv[i] = 1.0f / sqrtf((float)(d + 1));
        run += d;
    }
    if (tid == 1023) rowptr[N] = ssum[1023];
}

__global__ void fill_kernel(const int* __restrict__ src, const int* __restrict__ dst,
        int* __restrict__ cursor, int* __restrict__ colsrc, int E) {
    int e = blockIdx.x * blockDim.x + threadIdx.x;
    if (e < E) {
        int slot = atomicAdd(&cursor[dst[e]], 1);
        colsrc[slot] = src[e];
    }
}

// ---------------------------------------------------------------- GEMM (fp32)
// C[M,256] = act(A[M,256] @ W[256,256] + bias), act: 0=none, 1=celu
__global__ __launch_bounds__(256) void gemm256_kernel(const float* __restrict__ A,
        const float* __restrict__ W, const float* __restrict__ bias,
        float* __restrict__ C, int M, int act) {
    __shared__ float As[16][128];
    __shared__ float Bs[16][128];
    const int tid = threadIdx.x;
    const int row0 = blockIdx.x * 128, col0 = blockIdx.y * 128;
    const int tx = tid & 15, ty = tid >> 4;
    const int ar = tid >> 2;          // 0..63
    const int ak = (tid & 3) << 2;    // 0,4,8,12
    const int bk = tid >> 5;          // 0..7
    const int bn = (tid & 31) << 2;   // 0..124
    float acc[8][8] = {};

    for (int k0 = 0; k0 < 256; k0 += 16) {
#pragma unroll
        for (int s = 0; s < 2; s++) {
            int r = row0 + ar + s * 64;
            float4 v = make_float4(0.f, 0.f, 0.f, 0.f);
            if (r < M) v = *(const float4*)&A[(size_t)r * 256 + k0 + ak];
            As[ak + 0][ar + s * 64] = v.x;
            As[ak + 1][ar + s * 64] = v.y;
            As[ak + 2][ar + s * 64] = v.z;
            As[ak + 3][ar + s * 64] = v.w;
        }
#pragma unroll
        for (int s = 0; s < 2; s++) {
            int kr = k0 + bk + s * 8;
            *(float4*)&Bs[bk + s * 8][bn] = *(const float4*)&W[(size_t)kr * 256 + col0 + bn];
        }
        __syncthreads();
#pragma unroll
        for (int kk = 0; kk < 16; kk++) {
            float4 a0 = *(const float4*)&As[kk][ty * 4];
            float4 a1 = *(const float4*)&As[kk][ty * 4 + 64];
            float4 b0 = *(const float4*)&Bs[kk][tx * 4];
            float4 b1 = *(const float4*)&Bs[kk][tx * 4 + 64];
            float a[8] = {a0.x, a0.y, a0.z, a0.w, a1.x, a1.y, a1.z, a1.w};
            float b[8] = {b0.x, b0.y, b0.z, b0.w, b1.x, b1.y, b1.z, b1.w};
#pragma unroll
            for (int i = 0; i < 8; i++)
#pragma unroll
                for (int jj = 0; jj < 8; jj++)
                    acc[i][jj] = fmaf(a[i], b[jj], acc[i][jj]);
        }
        __syncthreads();
    }
#pragma unroll
    for (int i = 0; i < 8; i++) {
        int r = row0 + ((i < 4) ? (ty * 4 + i) : (64 + ty * 4 + i - 4));
        if (r >= M) continue;
#pragma unroll
        for (int half = 0; half < 2; half++) {
            int c = col0 + half * 64 + tx * 4;
            float vv[4];
#pragma unroll
            for (int jj = 0; jj < 4; jj++) {
                float v = acc[i][half * 4 + jj] + (bias ? bias[c + jj] : 0.f);
                if (act) v = v > 0.f ? v : expm1f(v);
                vv[jj] = v;
            }
            *(float4*)&C[(size_t)r * 256 + c] = make_float4(vv[0], vv[1], vv[2], vv[3]);
        }
    }
}

// ---------------------------------------------------------------- aggregation
// out[n] = postln(celu( sum_{e: dst=n} h[src_e]*dinv[src]*dinv[n] + h[n]*dinv[n]^2 + bias ))
__global__ __launch_bounds__(256) void agg_kernel(const float* __restrict__ h,
        const float* __restrict__ dinv, const int* __restrict__ rowptr,
        const int* __restrict__ colsrc, const float* __restrict__ bias,
        float* __restrict__ out, int doLN, const float* __restrict__ g,
        const float* __restrict__ lb) {
    __shared__ int sidx[64];
    __shared__ float sw[64];
    __shared__ float red[4];
    int node = blockIdx.x;
    int j = threadIdx.x;
    float di = dinv[node];
    float acc = h[(size_t)node * 256 + j] * di * di;
    int s0 = rowptr[node], s1 = rowptr[node + 1];
    for (int base = s0; base < s1; base += 64) {
        int cnt = min(64, s1 - base);
        if (j < cnt) {
            int s = colsrc[base + j];
            sidx[j] = s;
            sw[j] = dinv[s] * di;
        }
        __syncthreads();
        for (int i = 0; i < cnt; i++)
            acc = fmaf(h[(size_t)sidx[i] * 256 + j], sw[i], acc);
        __syncthreads();
    }
    acc += bias[j];
    acc = acc > 0.f ? acc : expm1f(acc);
    if (doLN) {
        int wid = j >> 6, lane = j & 63;
        float v = acc;
#pragma unroll
        for (int off = 32; off; off >>= 1) v += __shfl_down(v, off, 64);
        if (lane == 0) red[wid] = v;
        __syncthreads();
        float mu = (red[0] + red[1] + red[2] + red[3]) * (1.f / 256.f);
        __syncthreads();
        float d = acc - mu;
        v = d * d;
#pragma unroll
        for (int off = 32; off; off >>= 1) v += __shfl_down(v, off, 64);
        if (lane == 0) red[wid] = v;
        __syncthreads();
        float var = (red[0] + red[1] + red[2] + red[3]) * (1.f / 256.f);
        acc = d * rsqrtf(var + 1e-5f) * g[j] + lb[j];
    }
    out[(size_t)node * 256 + j] = acc;
}

// ---------------------------------------------------------------- final head
// out[M,25] = sigmoid(x[M,256] @ W[256,25] + b)
__global__ __launch_bounds__(256) void final_kernel(const float* __restrict__ x,
        const float* __restrict__ W, const float* __restrict__ b,
        float* __restrict__ out, int M) {
    __shared__ float sW[256 * 25];
    for (int i = threadIdx.x; i < 256 * 25; i += 256) sW[i] = W[i];
    __syncthreads();
    int group = threadIdx.x >> 5;  // 8 nodes per block
    int c = threadIdx.x & 31;
    int node = blockIdx.x * 8 + group;
    if (node >= M || c >= 25) return;
    const float4* xr = (const float4*)(x + (size_t)node * 256);
    float acc = b[c];
#pragma unroll 8
    for (int k4 = 0; k4 < 64; k4++) {
        float4 xv = xr[k4];
        int k = k4 * 4;
        acc = fmaf(xv.x, sW[(k + 0) * 25 + c],
              fmaf(xv.y, sW[(k + 1) * 25 + c],
              fmaf(xv.z, sW[(k + 2) * 25 + c],
              fmaf(xv.w, sW[(k + 3) * 25 + c], acc))));
    }
    out[(size_t)node * 25 + c] = 1.f / (1.f + expf(-acc));
}

// ---------------------------------------------------------------- launch

extern "C" void kernel_launch(void* const* d_in, const int* in_sizes, int n_in,
                              void* d_out, int out_size, void* d_ws, size_t ws_size,
                              hipStream_t stream) {
    const float* x       = (const float*)d_in[0];
    const int*   ei      = (const int*)d_in[1];
    const float* W_mlp   = (const float*)d_in[2];
    const float* b_mlp   = (const float*)d_in[3];
    const float* W_conv1 = (const float*)d_in[4];
    const float* b_conv1 = (const float*)d_in[5];
    const float* W_hid   = (const float*)d_in[6];
    const float* b_hid   = (const float*)d_in[7];
    const float* ln_g    = (const float*)d_in[8];
    const float* ln_b    = (const float*)d_in[9];
    const float* W_post  = (const float*)d_in[10];
    const float* b_post  = (const float*)d_in[11];
    const float* W_lin   = (const float*)d_in[12];
    const float* b_lin   = (const float*)d_in[13];
    float* out = (float*)d_out;

    const int N = in_sizes[0] / HID;   // 50000
    const int E = in_sizes[1] / 2;     // 800000
    const int* src = ei;
    const int* dst = ei + E;

    // workspace layout
    float* buf0   = (float*)d_ws;                 // N*256 floats
    float* buf1   = buf0 + (size_t)N * HID;       // N*256 floats
    float* dinv   = buf1 + (size_t)N * HID;       // N
    int*   deg    = (int*)(dinv + N);             // N
    int*   rowptr = deg + N;                      // N+1
    int*   cursor = rowptr + N + 1;               // N
    int*   colsrc = cursor + N;                   // E

    // ---- edge prep
    hipMemsetAsync(deg, 0, (size_t)N * sizeof(int), stream);
    hist_kernel<<<(E + 255) / 256, 256, 0, stream>>>(dst, deg, E);
    scan_kernel<<<1, 1024, 0, stream>>>(deg, rowptr, cursor, dinv, N);
    fill_kernel<<<(E + 255) / 256, 256, 0, stream>>>(src, dst, cursor, colsrc, E);

    dim3 gg((N + 127) / 128, 2);

    // ---- pre-MLP (2 layers, fused celu)
    gemm256_kernel<<<gg, 256, 0, stream>>>(x,    W_mlp,                 b_mlp,       buf0, N, 1);
    gemm256_kernel<<<gg, 256, 0, stream>>>(buf0, W_mlp + 256 * 256,     b_mlp + 256, buf1, N, 1);

    // ---- conv1: h = x@W, then agg+bias+celu
    gemm256_kernel<<<gg, 256, 0, stream>>>(buf1, W_conv1, nullptr, buf0, N, 0);
    agg_kernel<<<N, 256, 0, stream>>>(buf0, dinv, rowptr, colsrc, b_conv1, buf1, 0, nullptr, nullptr);

    // ---- hidden convs (celu + layernorm)
    for (int i = 0; i < 3; i++) {
        gemm256_kernel<<<gg, 256, 0, stream>>>(buf1, W_hid + (size_t)i * 256 * 256, nullptr, buf0, N, 0);
        agg_kernel<<<N, 256, 0, stream>>>(buf0, dinv, rowptr, colsrc, b_hid + i * 256, buf1, 1, ln_g, ln_b);
    }

    // ---- post-MLP (2 layers, fused celu)
    gemm256_kernel<<<gg, 256, 0, stream>>>(buf1, W_post,             b_post,       buf0, N, 1);
    gemm256_kernel<<<gg, 256, 0, stream>>>(buf0, W_post + 256 * 256, b_post + 256, buf1, N, 1);

    // ---- head + sigmoid
    final_kernel<<<(N + 7) / 8, 256, 0, stream>>>(buf1, W_lin, b_lin, out, N);
}

// Round 2
// 1210.678 us; speedup vs baseline: 1.4412x; 1.4412x over previous
//
#include <hip/hip_runtime.h>
#include <hip/hip_bf16.h>
#include <math.h>

#define HID 256

typedef __attribute__((ext_vector_type(4))) float f32x4;
typedef __attribute__((ext_vector_type(8))) short bf16x8;

static __device__ __forceinline__ unsigned short bftrunc(float v) {
    return (unsigned short)(__float_as_uint(v) >> 16);
}
static __device__ __forceinline__ unsigned short bfrtne(float v) {
    unsigned u = __float_as_uint(v);
    unsigned r = u + 0x7FFFu + ((u >> 16) & 1u);
    return (unsigned short)(r >> 16);
}
static __device__ __forceinline__ float bf2f(unsigned short s) {
    return __uint_as_float(((unsigned)s) << 16);
}

// ---------------------------------------------------------------- edge prep

__global__ void hist_kernel(const int* __restrict__ dst, int* __restrict__ deg, int E) {
    int e = blockIdx.x * blockDim.x + threadIdx.x;
    if (e < E) atomicAdd(&deg[dst[e]], 1);
}

__global__ __launch_bounds__(1024) void scan_kernel(const int* __restrict__ deg,
        int* __restrict__ rowptr, int* __restrict__ cursor,
        float* __restrict__ dinv, int N) {
    __shared__ int ssum[1024];
    int tid = threadIdx.x;
    int chunk = (N + 1023) / 1024;
    int lo = tid * chunk, hi = min(lo + chunk, N);
    int local = 0;
    for (int i = lo; i < hi; i++) local += deg[i];
    ssum[tid] = local;
    __syncthreads();
    for (int off = 1; off < 1024; off <<= 1) {
        int v = (tid >= off) ? ssum[tid - off] : 0;
        __syncthreads();
        ssum[tid] += v;
        __syncthreads();
    }
    int run = ssum[tid] - local;  // exclusive prefix
    for (int i = lo; i < hi; i++) {
        int d = deg[i];
        rowptr[i] = run;
        cursor[i] = run;
        dinv[i] = 1.0f / sqrtf((float)(d + 1));
        run += d;
    }
    if (tid == 1023) rowptr[N] = ssum[1023];
}

__global__ void fill_kernel(const int* __restrict__ src, const int* __restrict__ dst,
        int* __restrict__ cursor, int* __restrict__ colsrc, int E) {
    int e = blockIdx.x * blockDim.x + threadIdx.x;
    if (e < E) {
        int slot = atomicAdd(&cursor[dst[e]], 1);
        colsrc[slot] = src[e];
    }
}

// ---------------------------------------------------------------- weight split
// Produce Bt_hi/Bt_lo [n][k] bf16 planes (transposed W) for 8 weight matrices.
struct WPtrs { const float* w[8]; };

__global__ __launch_bounds__(256) void convw_kernel(WPtrs wp,
        unsigned short* __restrict__ bth, unsigned short* __restrict__ btl) {
    __shared__ unsigned short SH[64][72];
    __shared__ unsigned short SL[64][72];
    int mat = blockIdx.y;
    int tk = blockIdx.x >> 2, tn = blockIdx.x & 3;  // 64x64 tile coords
    const float* W = wp.w[mat];
    int kr = threadIdx.x >> 2, nc = (threadIdx.x & 3) * 16;
    const float* p = W + (size_t)(tk * 64 + kr) * 256 + tn * 64 + nc;
#pragma unroll
    for (int i = 0; i < 16; i++) {
        float v = p[i];
        unsigned short h = bftrunc(v);
        unsigned short l = bftrunc(v - bf2f(h));
        SH[nc + i][kr] = h;
        SL[nc + i][kr] = l;
    }
    __syncthreads();
    int nr = threadIdx.x >> 2, kc = (threadIdx.x & 3) * 16;
    size_t ob = (size_t)mat * 65536 + (size_t)(tn * 64 + nr) * 256 + tk * 64 + kc;
#pragma unroll
    for (int i = 0; i < 16; i++) {
        bth[ob + i] = SH[nr][kc + i];
        btl[ob + i] = SL[nr][kc + i];
    }
}

// ---------------------------------------------------------------- GEMM (split-bf16 MFMA)
// C[M,256] = act(A[M,256] @ W[256,256] + bias)
// W supplied as transposed bf16 hi/lo planes Bt[n][k].
// ACT: celu; OBF16: write bf16 (RTNE) instead of fp32.
#define LDA 40  // bf16 elems per LDS row (32 + 8 pad), 80B stride (16B-aligned)

template<int ACT, int OBF16>
__global__ __launch_bounds__(256) void gemm_mfma_kernel(
        const float* __restrict__ A,
        const unsigned short* __restrict__ BtH, const unsigned short* __restrict__ BtL,
        const float* __restrict__ bias, void* __restrict__ Cv, int M) {
    __shared__ unsigned short AsH[128 * LDA];
    __shared__ unsigned short AsL[128 * LDA];
    const int tid = threadIdx.x;
    const int row0 = blockIdx.x * 128, col0 = blockIdx.y * 128;
    const int wave = tid >> 6, lane = tid & 63;
    const int wm = wave >> 1, wn = wave & 1;           // 2x2 wave grid, 64x64/wave
    const int lr = lane & 15, lk = (lane >> 4) * 8;    // frag row/col, k offset
    const int srow = tid >> 1, skc = (tid & 1) * 16;   // staging: 2 thr/row, 16 k each
    const int arow = row0 + srow;

    f32x4 acc[4][4];
#pragma unroll
    for (int m = 0; m < 4; m++)
#pragma unroll
        for (int n = 0; n < 4; n++) acc[m][n] = (f32x4)0.0f;

    for (int k0 = 0; k0 < 256; k0 += 32) {
        // ---- stage A tile (128x32 fp32 -> hi/lo bf16 in LDS)
        float v[16];
        if (arow < M) {
            const float* ap = A + (size_t)arow * 256 + k0 + skc;
#pragma unroll
            for (int q = 0; q < 4; q++) *(f32x4*)&v[q * 4] = *(const f32x4*)(ap + q * 4);
        } else {
#pragma unroll
            for (int i = 0; i < 16; i++) v[i] = 0.0f;
        }
        bf16x8 h0, h1, l0, l1;
#pragma unroll
        for (int i = 0; i < 8; i++) {
            unsigned short hh = bftrunc(v[i]);
            h0[i] = (short)hh;
            l0[i] = (short)bftrunc(v[i] - bf2f(hh));
            unsigned short hh2 = bftrunc(v[i + 8]);
            h1[i] = (short)hh2;
            l1[i] = (short)bftrunc(v[i + 8] - bf2f(hh2));
        }
        *(bf16x8*)&AsH[srow * LDA + skc] = h0;
        *(bf16x8*)&AsH[srow * LDA + skc + 8] = h1;
        *(bf16x8*)&AsL[srow * LDA + skc] = l0;
        *(bf16x8*)&AsL[srow * LDA + skc + 8] = l1;
        __syncthreads();

        // ---- fragments
        bf16x8 ah[4], al[4], bh[4], bl[4];
#pragma unroll
        for (int m = 0; m < 4; m++) {
            int r = (wm * 64 + m * 16 + lr) * LDA + lk;
            ah[m] = *(const bf16x8*)&AsH[r];
            al[m] = *(const bf16x8*)&AsL[r];
        }
#pragma unroll
        for (int n = 0; n < 4; n++) {
            size_t boff = (size_t)(col0 + wn * 64 + n * 16 + lr) * 256 + k0 + lk;
            bh[n] = *(const bf16x8*)&BtH[boff];
            bl[n] = *(const bf16x8*)&BtL[boff];
        }
#pragma unroll
        for (int m = 0; m < 4; m++)
#pragma unroll
            for (int n = 0; n < 4; n++) {
                acc[m][n] = __builtin_amdgcn_mfma_f32_16x16x32_bf16(ah[m], bh[n], acc[m][n], 0, 0, 0);
                acc[m][n] = __builtin_amdgcn_mfma_f32_16x16x32_bf16(ah[m], bl[n], acc[m][n], 0, 0, 0);
                acc[m][n] = __builtin_amdgcn_mfma_f32_16x16x32_bf16(al[m], bh[n], acc[m][n], 0, 0, 0);
            }
        __syncthreads();
    }

    // ---- epilogue: C/D layout col=lane&15, row=(lane>>4)*4+j (m89-verified)
#pragma unroll
    for (int m = 0; m < 4; m++) {
        int rb = row0 + wm * 64 + m * 16 + (lane >> 4) * 4;
#pragma unroll
        for (int n = 0; n < 4; n++) {
            int col = col0 + wn * 64 + n * 16 + lr;
            float bv = bias ? bias[col] : 0.0f;
#pragma unroll
            for (int j = 0; j < 4; j++) {
                int r = rb + j;
                if (r < M) {
                    float x = acc[m][n][j] + bv;
                    if (ACT) x = x > 0.0f ? x : expm1f(x);
                    if (OBF16)
                        ((unsigned short*)Cv)[(size_t)r * 256 + col] = bfrtne(x);
                    else
                        ((float*)Cv)[(size_t)r * 256 + col] = x;
                }
            }
        }
    }
}

// ---------------------------------------------------------------- aggregation
// h is bf16 [N,256]. out fp32. 128 threads/node, 2 features/thread (bf16x2 loads).
__global__ __launch_bounds__(128) void agg_kernel(const unsigned short* __restrict__ h,
        const float* __restrict__ dinv, const int* __restrict__ rowptr,
        const int* __restrict__ colsrc, const float* __restrict__ bias,
        float* __restrict__ out, int doLN, const float* __restrict__ g,
        const float* __restrict__ lb) {
    __shared__ int sidx[64];
    __shared__ float sw[64];
    __shared__ float red[2];
    int node = blockIdx.x;
    int t = threadIdx.x;
    float di = dinv[node];
    unsigned u0 = ((const unsigned*)(h + (size_t)node * 256))[t];
    float acc0 = bf2f((unsigned short)u0) * di * di;
    float acc1 = bf2f((unsigned short)(u0 >> 16)) * di * di;
    int s0 = rowptr[node], s1 = rowptr[node + 1];
    for (int base = s0; base < s1; base += 64) {
        int cnt = min(64, s1 - base);
        if (t < cnt) {
            int s = colsrc[base + t];
            sidx[t] = s;
            sw[t] = dinv[s] * di;
        }
        __syncthreads();
        for (int i = 0; i < cnt; i++) {
            unsigned uu = ((const unsigned*)(h + (size_t)sidx[i] * 256))[t];
            float w = sw[i];
            acc0 = fmaf(bf2f((unsigned short)uu), w, acc0);
            acc1 = fmaf(bf2f((unsigned short)(uu >> 16)), w, acc1);
        }
        __syncthreads();
    }
    int j0 = t * 2;
    acc0 += bias[j0];
    acc1 += bias[j0 + 1];
    acc0 = acc0 > 0.0f ? acc0 : expm1f(acc0);
    acc1 = acc1 > 0.0f ? acc1 : expm1f(acc1);
    if (doLN) {
        int wid = t >> 6, lane = t & 63;
        float v = acc0 + acc1;
#pragma unroll
        for (int off = 32; off; off >>= 1) v += __shfl_down(v, off, 64);
        if (lane == 0) red[wid] = v;
        __syncthreads();
        float mu = (red[0] + red[1]) * (1.0f / 256.0f);
        __syncthreads();
        float d0 = acc0 - mu, d1 = acc1 - mu;
        v = d0 * d0 + d1 * d1;
#pragma unroll
        for (int off = 32; off; off >>= 1) v += __shfl_down(v, off, 64);
        if (lane == 0) red[wid] = v;
        __syncthreads();
        float var = (red[0] + red[1]) * (1.0f / 256.0f);
        float rs = rsqrtf(var + 1e-5f);
        acc0 = d0 * rs * g[j0] + lb[j0];
        acc1 = d1 * rs * g[j0 + 1] + lb[j0 + 1];
    }
    *(float2*)&out[(size_t)node * 256 + j0] = make_float2(acc0, acc1);
}

// ---------------------------------------------------------------- final head
__global__ __launch_bounds__(256) void final_kernel(const float* __restrict__ x,
        const float* __restrict__ W, const float* __restrict__ b,
        float* __restrict__ out, int M) {
    __shared__ float sW[256 * 25];
    for (int i = threadIdx.x; i < 256 * 25; i += 256) sW[i] = W[i];
    __syncthreads();
    int group = threadIdx.x >> 5;  // 8 nodes per block
    int c = threadIdx.x & 31;
    int node = blockIdx.x * 8 + group;
    if (node >= M || c >= 25) return;
    const float4* xr = (const float4*)(x + (size_t)node * 256);
    float acc = b[c];
#pragma unroll 8
    for (int k4 = 0; k4 < 64; k4++) {
        float4 xv = xr[k4];
        int k = k4 * 4;
        acc = fmaf(xv.x, sW[(k + 0) * 25 + c],
              fmaf(xv.y, sW[(k + 1) * 25 + c],
              fmaf(xv.z, sW[(k + 2) * 25 + c],
              fmaf(xv.w, sW[(k + 3) * 25 + c], acc))));
    }
    out[(size_t)node * 25 + c] = 1.0f / (1.0f + expf(-acc));
}

// ---------------------------------------------------------------- launch

extern "C" void kernel_launch(void* const* d_in, const int* in_sizes, int n_in,
                              void* d_out, int out_size, void* d_ws, size_t ws_size,
                              hipStream_t stream) {
    const float* x       = (const float*)d_in[0];
    const int*   ei      = (const int*)d_in[1];
    const float* W_mlp   = (const float*)d_in[2];
    const float* b_mlp   = (const float*)d_in[3];
    const float* W_conv1 = (const float*)d_in[4];
    const float* b_conv1 = (const float*)d_in[5];
    const float* W_hid   = (const float*)d_in[6];
    const float* b_hid   = (const float*)d_in[7];
    const float* ln_g    = (const float*)d_in[8];
    const float* ln_b    = (const float*)d_in[9];
    const float* W_post  = (const float*)d_in[10];
    const float* b_post  = (const float*)d_in[11];
    const float* W_lin   = (const float*)d_in[12];
    const float* b_lin   = (const float*)d_in[13];
    float* out = (float*)d_out;

    const int N = in_sizes[0] / HID;   // 50000
    const int E = in_sizes[1] / 2;     // 800000
    const int* src = ei;
    const int* dst = ei + E;

    // workspace layout
    float* buf0   = (float*)d_ws;                   // N*256 fp32 (aliased as bf16 for conv h)
    float* buf1   = buf0 + (size_t)N * HID;         // N*256 fp32
    float* dinv   = buf1 + (size_t)N * HID;         // N
    int*   deg    = (int*)(dinv + N);               // N
    int*   rowptr = deg + N;                        // N+1
    int*   cursor = rowptr + N + 1;                 // N
    int*   colsrc = cursor + N;                     // E
    unsigned short* bth = (unsigned short*)(colsrc + E);  // 8*65536 bf16
    unsigned short* btl = bth + 8 * 65536;                // 8*65536 bf16
    unsigned short* hbf = (unsigned short*)buf0;          // bf16 view of buf0

    // ---- weight split (8 matrices -> transposed hi/lo bf16 planes)
    WPtrs wp;
    wp.w[0] = W_mlp;
    wp.w[1] = W_mlp + 65536;
    wp.w[2] = W_conv1;
    wp.w[3] = W_hid;
    wp.w[4] = W_hid + 65536;
    wp.w[5] = W_hid + 2 * 65536;
    wp.w[6] = W_post;
    wp.w[7] = W_post + 65536;
    convw_kernel<<<dim3(16, 8), 256, 0, stream>>>(wp, bth, btl);

    // ---- edge prep
    hipMemsetAsync(deg, 0, (size_t)N * sizeof(int), stream);
    hist_kernel<<<(E + 255) / 256, 256, 0, stream>>>(dst, deg, E);
    scan_kernel<<<1, 1024, 0, stream>>>(deg, rowptr, cursor, dinv, N);
    fill_kernel<<<(E + 255) / 256, 256, 0, stream>>>(src, dst, cursor, colsrc, E);

    dim3 gg((N + 127) / 128, 2);
    const size_t WM = 65536;

    // ---- pre-MLP (2 layers, fused celu, fp32 out)
    gemm_mfma_kernel<1, 0><<<gg, 256, 0, stream>>>(x,    bth + 0 * WM, btl + 0 * WM, b_mlp,       buf1, N);
    // NOTE: first layer writes buf1? No -- keep ping-pong: x->buf0, buf0->buf1.
    // (corrected sequence below)
    gemm_mfma_kernel<1, 0><<<gg, 256, 0, stream>>>(buf1, bth + 1 * WM, btl + 1 * WM, b_mlp + 256, buf0, N);

    // ---- conv1: h = x@W (bf16 out), then agg+bias+celu (fp32 out)
    gemm_mfma_kernel<0, 1><<<gg, 256, 0, stream>>>(buf0, bth + 2 * WM, btl + 2 * WM, nullptr, buf1, N);
    // conv h must land in a buffer not being read: write bf16 into buf... see below.

    // The above three launches have buffer roles tangled; redo cleanly:
    // (the harness only runs kernel_launch once per call, so just launch the
    // correct sequence -- the three launches above already computed:
    //   buf1 = celu(x@W0+b0); buf0 = celu(buf1@W1+b1); buf1 = bf16(buf0@Wc) [as bf16 in fp32 buffer]
    // which is exactly the ping-pong we want with hbf1 = (ushort*)buf1.)
    unsigned short* hbf1 = (unsigned short*)buf1;

    agg_kernel<<<N, 128, 0, stream>>>(hbf1, dinv, rowptr, colsrc, b_conv1, buf0, 0, nullptr, nullptr);

    // ---- hidden convs (celu + layernorm): gemm buf0->bf16(buf1), agg buf1->buf0
    for (int i = 0; i < 3; i++) {
        gemm_mfma_kernel<0, 1><<<gg, 256, 0, stream>>>(buf0, bth + (size_t)(3 + i) * WM, btl + (size_t)(3 + i) * WM, nullptr, buf1, N);
        agg_kernel<<<N, 128, 0, stream>>>(hbf1, dinv, rowptr, colsrc, b_hid + i * 256, buf0, 1, ln_g, ln_b);
    }

    // ---- post-MLP (2 layers, fused celu, fp32)
    gemm_mfma_kernel<1, 0><<<gg, 256, 0, stream>>>(buf0, bth + 6 * WM, btl + 6 * WM, b_post,       buf1, N);
    gemm_mfma_kernel<1, 0><<<gg, 256, 0, stream>>>(buf1, bth + 7 * WM, btl + 7 * WM, b_post + 256, buf0, N);

    // ---- head + sigmoid
    final_kernel<<<(N + 7) / 8, 256, 0, stream>>>(buf0, W_lin, b_lin, out, N);
    (void)hbf; (void)ws_size; (void)n_in; (void)out_size;
}